// Round 2
// baseline (497.197 us; speedup 1.0000x reference)
//
#include <hip/hip_runtime.h>
#include <math.h>

#define H 1024
#define SEQ 512
#define VOCAB 50257
#define VROWS 64                      // rows per block in vocab kernel
#define VNBLK ((VOCAB + VROWS - 1) / VROWS)   // 786

// workspace offsets (floats)
#define OFF_ALOGIT  0        // 512   attention logits
#define OFF_APPLIED 512      // 1024  attn_applied (atomicAdd -> zeroed by K1)
#define OFF_X       1536     // 1024  relu(comb)
#define OFF_H       2560     // 1024  new h
#define OFF_VLOGIT  3584     // 50257 vocab logits
#define OFF_PM      53844    // 786   per-block partial max
#define OFF_PS      54632    // 786   per-block partial sumexp
#define OFF_RED     55420    // [unused, lse]
#define OFF_CNT     55424    // int counter (zeroed by K1)

// d_out layout: out[50257] | h[1024] | c[1024] | attn_weights[512]
#define OUT_H   50257
#define OUT_C   (50257 + 1024)
#define OUT_AW  (50257 + 2048)

__device__ __forceinline__ float wave_sum(float v) {
    for (int off = 32; off; off >>= 1) v += __shfl_down(v, off, 64);
    return v;
}
__device__ __forceinline__ float wave_max(float v) {
    for (int off = 32; off; off >>= 1) v = fmaxf(v, __shfl_down(v, off, 64));
    return v;
}
__device__ __forceinline__ float dot4(float4 a, float4 b) {
    return a.x * b.x + a.y * b.y + a.z * b.z + a.w * b.w;
}

// ---- K1: attention logits (512 blocks); blocks 0..3 also zero applied; b0 zeros counter
__global__ void k_attn_logits(const float* __restrict__ emb, const int* __restrict__ idx,
                              const float* __restrict__ h0, const float* __restrict__ attn_W,
                              const float* __restrict__ attn_b, float* __restrict__ ws) {
    __shared__ float red[4];
    const int s = blockIdx.x, t = threadIdx.x;
    if (s < 4) ws[OFF_APPLIED + s * 256 + t] = 0.f;
    if (s == 0 && t == 0)
        __hip_atomic_store((int*)(ws + OFF_CNT), 0, __ATOMIC_RELAXED, __HIP_MEMORY_SCOPE_AGENT);

    const float4* erow = (const float4*)(emb + (long)idx[0] * H);
    const float4* h04  = (const float4*)h0;
    const float4* wrow = (const float4*)(attn_W + (long)s * (2 * H));
    float acc;
    if (t < 128) {
        acc = dot4(erow[t * 2], wrow[t * 2]) + dot4(erow[t * 2 + 1], wrow[t * 2 + 1]);
    } else {
        int u = t - 128;
        acc = dot4(h04[u * 2], wrow[t * 2]) + dot4(h04[u * 2 + 1], wrow[t * 2 + 1]);
    }
    acc = wave_sum(acc);
    if ((t & 63) == 0) red[t >> 6] = acc;
    __syncthreads();
    if (t == 0) ws[OFF_ALOGIT + s] = red[0] + red[1] + red[2] + red[3] + attn_b[s];
}

// ---- K2: softmax (recomputed per block from LDS) + attn_applied split-K atomics
//      grid 64: hb = b&3 (256-col chunk), sc = b>>2 (32-seq chunk)
__global__ void k_softmax_applied(const float* __restrict__ enc, float* __restrict__ ws,
                                  float* __restrict__ out_aw) {
    __shared__ float wsm[SEQ];
    __shared__ float red[4];
    __shared__ float bc;
    const int t = threadIdx.x, lane = t & 63, wid = t >> 6;
    const int hb = blockIdx.x & 3, sc = blockIdx.x >> 2;

    float v0 = ws[OFF_ALOGIT + t];
    float v1 = ws[OFF_ALOGIT + 256 + t];
    float m = wave_max(fmaxf(v0, v1));
    if (lane == 0) red[wid] = m;
    __syncthreads();
    if (t == 0) bc = fmaxf(fmaxf(red[0], red[1]), fmaxf(red[2], red[3]));
    __syncthreads();
    float e0 = __expf(v0 - bc), e1 = __expf(v1 - bc);
    float sm = wave_sum(e0 + e1);
    __syncthreads();
    if (lane == 0) red[wid] = sm;
    __syncthreads();
    if (t == 0) bc = red[0] + red[1] + red[2] + red[3];
    __syncthreads();
    float w0 = e0 / bc, w1 = e1 / bc;
    wsm[t] = w0;
    wsm[256 + t] = w1;
    if (blockIdx.x == 0) { out_aw[t] = w0; out_aw[256 + t] = w1; }
    __syncthreads();

    const int h = hb * 256 + t;
    const int s0 = sc * 32;
    float acc = 0.f;
    #pragma unroll 8
    for (int s = s0; s < s0 + 32; ++s)
        acc += wsm[s] * enc[s * H + h];
    atomicAdd(&ws[OFF_APPLIED + h], acc);
}

// ---- K3: x[h] = relu(dot(concat(emb[idx], applied), comb_W[h]) + comb_b[h])
__global__ void k_comb(const float* __restrict__ emb, const int* __restrict__ idx,
                       const float* __restrict__ comb_W, const float* __restrict__ comb_b,
                       float* __restrict__ ws) {
    __shared__ float red[4];
    const int h = blockIdx.x, t = threadIdx.x;
    const float4* erow = (const float4*)(emb + (long)idx[0] * H);
    const float4* ap4  = (const float4*)(ws + OFF_APPLIED);
    const float4* wrow = (const float4*)(comb_W + (long)h * (2 * H));
    float acc;
    if (t < 128) {
        acc = dot4(erow[t * 2], wrow[t * 2]) + dot4(erow[t * 2 + 1], wrow[t * 2 + 1]);
    } else {
        int u = t - 128;
        acc = dot4(ap4[u * 2], wrow[t * 2]) + dot4(ap4[u * 2 + 1], wrow[t * 2 + 1]);
    }
    acc = wave_sum(acc);
    if ((t & 63) == 0) red[t >> 6] = acc;
    __syncthreads();
    if (t == 0) ws[OFF_X + h] = fmaxf(red[0] + red[1] + red[2] + red[3] + comb_b[h], 0.f);
}

// ---- K4: fused gates + LSTM elementwise. Block j computes all 4 gates for h=j.
__global__ void k_gates_lstm(const float* __restrict__ w_ih, const float* __restrict__ w_hh,
                             const float* __restrict__ b_ih, const float* __restrict__ b_hh,
                             const float* __restrict__ h0, const float* __restrict__ c0,
                             float* __restrict__ ws, float* __restrict__ dout) {
    __shared__ float red[16];   // [wave][gate]
    const int j = blockIdx.x, t = threadIdx.x, lane = t & 63, wid = t >> 6;
    const float4 xv = ((const float4*)(ws + OFF_X))[t];
    const float4 hv = ((const float4*)h0)[t];
    float acc[4];
    #pragma unroll
    for (int g = 0; g < 4; ++g) {
        const float4* wi = (const float4*)(w_ih + (long)(g * H + j) * H);
        const float4* wh = (const float4*)(w_hh + (long)(g * H + j) * H);
        acc[g] = dot4(xv, wi[t]) + dot4(hv, wh[t]);
    }
    #pragma unroll
    for (int g = 0; g < 4; ++g) {
        acc[g] = wave_sum(acc[g]);
        if (lane == 0) red[wid * 4 + g] = acc[g];
    }
    __syncthreads();
    if (t == 0) {
        float gv[4];
        #pragma unroll
        for (int g = 0; g < 4; ++g)
            gv[g] = red[g] + red[4 + g] + red[8 + g] + red[12 + g]
                  + b_ih[g * H + j] + b_hh[g * H + j];
        float i = 1.f / (1.f + __expf(-gv[0]));
        float f = 1.f / (1.f + __expf(-gv[1]));
        float g_ = tanhf(gv[2]);
        float o = 1.f / (1.f + __expf(-gv[3]));
        float c = f * c0[j] + i * g_;
        float h = o * tanhf(c);
        dout[OUT_H + j] = h;
        dout[OUT_C + j] = c;
        ws[OFF_H + j] = h;
    }
}

// ---- K5: vocab logits + per-block online-softmax partials + last-block LSE reduce
__global__ void k_vocab(const float* __restrict__ out_W, const float* __restrict__ out_b,
                        float* __restrict__ ws) {
    __shared__ __align__(16) float hs[H];
    __shared__ float red_m[4], red_s[4];
    __shared__ int lastFlag;
    const int t = threadIdx.x, lane = t & 63, wid = t >> 6;
    ((float4*)hs)[t] = ((const float4*)(ws + OFF_H))[t];
    __syncthreads();
    const float4* hs4 = (const float4*)hs;

    const int base = blockIdx.x * VROWS;
    float m = -INFINITY, s = 0.f;
    #pragma unroll 4
    for (int i = 0; i < VROWS / 4; ++i) {
        const int r = base + i * 4 + wid;
        if (r < VOCAB) {
            const float4* wrow = (const float4*)(out_W + (long)r * H);
            float acc = 0.f;
            #pragma unroll
            for (int it = 0; it < 4; ++it) {
                int k = it * 64 + lane;
                acc += dot4(wrow[k], hs4[k]);
            }
            acc = wave_sum(acc);
            if (lane == 0) {
                float logit = acc + out_b[r];
                ws[OFF_VLOGIT + r] = logit;
                float M = fmaxf(m, logit);
                s = s * __expf(m - M) + __expf(logit - M);
                m = M;
            }
        }
    }
    if (lane == 0) { red_m[wid] = m; red_s[wid] = s; }
    __syncthreads();
    if (t == 0) {
        m = red_m[0]; s = red_s[0];
        #pragma unroll
        for (int w = 1; w < 4; ++w) {
            float M = fmaxf(m, red_m[w]);
            s = s * __expf(m - M) + red_s[w] * __expf(red_m[w] - M);
            m = M;
        }
        __hip_atomic_store(&ws[OFF_PM + blockIdx.x], m, __ATOMIC_RELAXED, __HIP_MEMORY_SCOPE_AGENT);
        __hip_atomic_store(&ws[OFF_PS + blockIdx.x], s, __ATOMIC_RELAXED, __HIP_MEMORY_SCOPE_AGENT);
        __threadfence();
        int old = __hip_atomic_fetch_add((int*)(ws + OFF_CNT), 1, __ATOMIC_ACQ_REL,
                                         __HIP_MEMORY_SCOPE_AGENT);
        lastFlag = (old == (int)gridDim.x - 1);
    }
    __syncthreads();
    if (lastFlag) {
        float lm = -INFINITY, ls = 0.f;
        for (int p = t; p < (int)gridDim.x; p += 256) {
            float pm = __hip_atomic_load(&ws[OFF_PM + p], __ATOMIC_RELAXED, __HIP_MEMORY_SCOPE_AGENT);
            float ps = __hip_atomic_load(&ws[OFF_PS + p], __ATOMIC_RELAXED, __HIP_MEMORY_SCOPE_AGENT);
            float M = fmaxf(lm, pm);
            ls = ls * __expf(lm - M) + ps * __expf(pm - M);
            lm = M;
        }
        for (int off = 32; off; off >>= 1) {
            float om = __shfl_down(lm, off, 64);
            float os = __shfl_down(ls, off, 64);
            float M = fmaxf(lm, om);
            ls = ls * __expf(lm - M) + os * __expf(om - M);
            lm = M;
        }
        if (lane == 0) { red_m[wid] = lm; red_s[wid] = ls; }
        __syncthreads();
        if (t == 0) {
            lm = red_m[0]; ls = red_s[0];
            #pragma unroll
            for (int w = 1; w < 4; ++w) {
                float M = fmaxf(lm, red_m[w]);
                ls = ls * __expf(lm - M) + red_s[w] * __expf(red_m[w] - M);
                lm = M;
            }
            ws[OFF_RED + 1] = lm + logf(ls);
        }
    }
}

// ---- K6: final log-softmax write
__global__ void k_write(const float* __restrict__ ws, float* __restrict__ dout) {
    const int v = blockIdx.x * 256 + threadIdx.x;
    if (v < VOCAB) dout[v] = ws[OFF_VLOGIT + v] - ws[OFF_RED + 1];
}

extern "C" void kernel_launch(void* const* d_in, const int* in_sizes, int n_in,
                              void* d_out, int out_size, void* d_ws, size_t ws_size,
                              hipStream_t stream) {
    const int*   idx    = (const int*)d_in[0];
    const float* h0     = (const float*)d_in[1];
    const float* c0     = (const float*)d_in[2];
    const float* enc    = (const float*)d_in[3];
    const float* emb    = (const float*)d_in[4];
    const float* attn_W = (const float*)d_in[5];
    const float* attn_b = (const float*)d_in[6];
    const float* comb_W = (const float*)d_in[7];
    const float* comb_b = (const float*)d_in[8];
    const float* w_ih   = (const float*)d_in[9];
    const float* w_hh   = (const float*)d_in[10];
    const float* b_ih   = (const float*)d_in[11];
    const float* b_hh   = (const float*)d_in[12];
    const float* out_W  = (const float*)d_in[13];
    const float* out_b  = (const float*)d_in[14];
    float* ws  = (float*)d_ws;
    float* out = (float*)d_out;

    k_attn_logits<<<SEQ, 256, 0, stream>>>(emb, idx, h0, attn_W, attn_b, ws);
    k_softmax_applied<<<64, 256, 0, stream>>>(enc, ws, out + OUT_AW);
    k_comb<<<H, 256, 0, stream>>>(emb, idx, comb_W, comb_b, ws);
    k_gates_lstm<<<H, 256, 0, stream>>>(w_ih, w_hh, b_ih, b_hh, h0, c0, ws, out);
    k_vocab<<<VNBLK, 256, 0, stream>>>(out_W, out_b, ws);
    k_write<<<(VOCAB + 255) / 256, 256, 0, stream>>>(ws, out);
}